// Round 1
// baseline (1067.652 us; speedup 1.0000x reference)
//
#include <hip/hip_runtime.h>
#include <hip/hip_bf16.h>
#include <stdint.h>

// Problem constants
#define NB    256   // batch
#define NSRC  512
#define NPRED 128
#define ND    512

typedef float  f32x4  __attribute__((ext_vector_type(4)));
typedef short  bf16x8 __attribute__((ext_vector_type(8)));
typedef unsigned short u16;
typedef unsigned int   u32;

__device__ __forceinline__ u16 bf16_rne(float x) {
    u32 u = __float_as_uint(x);
    u32 r = (u + 0x7FFFu + ((u >> 16) & 1u)) >> 16;
    return (u16)r;
}
__device__ __forceinline__ float bf2f(u16 h) {
    return __uint_as_float(((u32)h) << 16);
}

// ---------------------------------------------------------------------------
// K1: query = dec @ W^T  (M=32768, N=512, K=512), split-bf16 3-pass MFMA.
// Output: packed (hi<<16)|lo bf16 pair per element, written into d_out (u32).
// Tiles 128x128, BK=64, 256 threads (4 waves, 2x2).
// ---------------------------------------------------------------------------
#define K1ROW 72   // LDS row pitch in shorts (64 data + 8 pad -> conflict-free b128)

__global__ __launch_bounds__(256, 2)
void k_query(const float* __restrict__ dec, const float* __restrict__ W,
             u32* __restrict__ qout)
{
    extern __shared__ u16 lds1[];
    u16* Ah = lds1;                  // [128][72]
    u16* Al = Ah + 128 * K1ROW;
    u16* Bh = Al + 128 * K1ROW;
    u16* Bl = Bh + 128 * K1ROW;

    int bid = blockIdx.x;                       // 1024 blocks
    int wg  = (bid & 7) * 128 + (bid >> 3);     // XCD swizzle (1024 = 8*128)
    int tm  = wg >> 2;                          // 0..255
    int tn  = wg & 3;                           // 0..3
    int tid  = threadIdx.x;
    int lane = tid & 63;
    int wid  = tid >> 6;
    int wr = wid >> 1, wc = wid & 1;
    int ln = lane & 15, lg = lane >> 4;

    f32x4 acc[4][4];
#pragma unroll
    for (int i = 0; i < 4; ++i)
#pragma unroll
        for (int j = 0; j < 4; ++j) { acc[i][j][0]=0.f; acc[i][j][1]=0.f; acc[i][j][2]=0.f; acc[i][j][3]=0.f; }

    for (int kt = 0; kt < 8; ++kt) {
        if (kt) __syncthreads();
        // stage dec chunk (128x64) and W chunk (128x64), f32 -> bf16 hi/lo
#pragma unroll
        for (int i = 0; i < 8; ++i) {
            int flat = (i * 256 + tid) * 4;
            int r = flat >> 6, c = flat & 63;
            float4 va = *(const float4*)(dec + (size_t)(tm * 128 + r) * 512 + kt * 64 + c);
            ushort4 h, l;
            h.x = bf16_rne(va.x); l.x = bf16_rne(va.x - bf2f(h.x));
            h.y = bf16_rne(va.y); l.y = bf16_rne(va.y - bf2f(h.y));
            h.z = bf16_rne(va.z); l.z = bf16_rne(va.z - bf2f(h.z));
            h.w = bf16_rne(va.w); l.w = bf16_rne(va.w - bf2f(h.w));
            *(ushort4*)(Ah + r * K1ROW + c) = h;
            *(ushort4*)(Al + r * K1ROW + c) = l;
            float4 vb = *(const float4*)(W + (size_t)(tn * 128 + r) * 512 + kt * 64 + c);
            ushort4 hb, lb;
            hb.x = bf16_rne(vb.x); lb.x = bf16_rne(vb.x - bf2f(hb.x));
            hb.y = bf16_rne(vb.y); lb.y = bf16_rne(vb.y - bf2f(hb.y));
            hb.z = bf16_rne(vb.z); lb.z = bf16_rne(vb.z - bf2f(hb.z));
            hb.w = bf16_rne(vb.w); lb.w = bf16_rne(vb.w - bf2f(hb.w));
            *(ushort4*)(Bh + r * K1ROW + c) = hb;
            *(ushort4*)(Bl + r * K1ROW + c) = lb;
        }
        __syncthreads();
#pragma unroll
        for (int ks = 0; ks < 2; ++ks) {
            int ko = ks * 32 + lg * 8;
            bf16x8 ah[4], al[4], bh[4], bl[4];
#pragma unroll
            for (int ms = 0; ms < 4; ++ms) {
                int m = wr * 64 + ms * 16 + ln;
                ah[ms] = *(const bf16x8*)(Ah + m * K1ROW + ko);
                al[ms] = *(const bf16x8*)(Al + m * K1ROW + ko);
            }
#pragma unroll
            for (int ns = 0; ns < 4; ++ns) {
                int n = wc * 64 + ns * 16 + ln;
                bh[ns] = *(const bf16x8*)(Bh + n * K1ROW + ko);
                bl[ns] = *(const bf16x8*)(Bl + n * K1ROW + ko);
            }
#pragma unroll
            for (int ms = 0; ms < 4; ++ms)
#pragma unroll
                for (int ns = 0; ns < 4; ++ns) {
                    acc[ms][ns] = __builtin_amdgcn_mfma_f32_16x16x32_bf16(ah[ms], bh[ns], acc[ms][ns], 0, 0, 0);
                    acc[ms][ns] = __builtin_amdgcn_mfma_f32_16x16x32_bf16(ah[ms], bl[ns], acc[ms][ns], 0, 0, 0);
                    acc[ms][ns] = __builtin_amdgcn_mfma_f32_16x16x32_bf16(al[ms], bh[ns], acc[ms][ns], 0, 0, 0);
                }
        }
    }
    // epilogue: pack query as bf16 hi/lo into u32
#pragma unroll
    for (int ms = 0; ms < 4; ++ms)
#pragma unroll
        for (int ns = 0; ns < 4; ++ns)
#pragma unroll
            for (int j = 0; j < 4; ++j) {
                int r = tm * 128 + wr * 64 + ms * 16 + lg * 4 + j;
                int c = tn * 128 + wc * 64 + ns * 16 + ln;
                float v = acc[ms][ns][j];
                u16 hi = bf16_rne(v);
                u16 lo = bf16_rne(v - bf2f(hi));
                qout[(size_t)r * 512 + c] = ((u32)hi << 16) | (u32)lo;
            }
}

// ---------------------------------------------------------------------------
// K2: fused scores + mask + softmax + PV.  One block = (b, 64 query rows).
// 512 threads = 8 waves (wm 0..3 over M, wn 0..1 over N).
// Phase A: S(64x512) in regs via split-bf16 3-pass. Phase B: two-pass softmax.
// Phase C: ctx = weights(bf16,LDS) @ enc(bf16,LDS transposed, padded rows).
// ---------------------------------------------------------------------------
#define QROW 72    // Qh/Ql row pitch (shorts)
#define EROW 72    // Eh/El row pitch (shorts)
#define WROW 528   // wlds row pitch (shorts): 512 + 16 pad
#define TROW 40    // eldsT row pitch (shorts): 32 + 8 pad

__global__ __launch_bounds__(512, 2)
void k_attn(const float* __restrict__ enc, const u32* qpk,
            const void* __restrict__ maskraw, float* out)
{
    extern __shared__ char smem[];
    u16* Qh = (u16*)smem;                         // [64][72]
    u16* Ql = Qh + 64 * QROW;
    u16* Eh = Ql + 64 * QROW;                     // [128][72]
    u16* El = Eh + 128 * EROW;
    u16* wlds  = (u16*)smem;                      // [64][528]  (phase C, overlaps phase A)
    u16* eldsT = (u16*)(smem + 64 * WROW * 2);    // [512][40]
    float* scrM = (float*)(smem + 64 * WROW * 2 + 512 * TROW * 2);  // [2][64]
    float* scrS = scrM + 128;                                        // [2][64]
    int* flagsh = (int*)(scrS + 128);

    int tid  = threadIdx.x;
    int lane = tid & 63, wid = tid >> 6;
    int wm = wid >> 1, wn = wid & 1;
    int ln = lane & 15, lg = lane >> 4;

    int bid = blockIdx.x;                    // 512 blocks
    int wg  = (bid & 7) * 64 + (bid >> 3);   // XCD swizzle: both halves of a b share an XCD
    int b   = wg >> 1;
    int ph  = wg & 1;
    int brow0 = b * 128 + ph * 64;

    // ---- mask element-size detection (1-byte vs 4-byte encodings) ----
    const int* mi = (const int*)maskraw;
    int bad = 0;
    for (int i = tid; i < 1024; i += 512) {
        int v = mi[i];
        if (!(v == 0 || v == 1 || v == 0x3F800000)) bad = 1;
    }
    if (tid == 0) *flagsh = 0;
    __syncthreads();
    if (bad) atomicOr(flagsh, 1);
    __syncthreads();
    const int mbyte = *flagsh;   // 1 -> byte layout, 0 -> 4-byte (int or f32; nonzero test works)

    // ---- Phase A: scores ----
    f32x4 acc[16];
#pragma unroll
    for (int t = 0; t < 16; ++t) { acc[t][0]=0.f; acc[t][1]=0.f; acc[t][2]=0.f; acc[t][3]=0.f; }

    for (int it = 0; it < 32; ++it) {
        int dc = it >> 2, ns = it & 3;
        if ((it & 3) == 0) {
            // stage Q chunk 64x64 (packed hi/lo)
#pragma unroll
            for (int i = 0; i < 2; ++i) {
                int flat = (i * 512 + tid) * 4;
                int r = flat >> 6, c = flat & 63;
                uint4 v = *(const uint4*)(qpk + (size_t)(brow0 + r) * 512 + dc * 64 + c);
                ushort4 h, l;
                h.x = (u16)(v.x >> 16); l.x = (u16)(v.x & 0xFFFF);
                h.y = (u16)(v.y >> 16); l.y = (u16)(v.y & 0xFFFF);
                h.z = (u16)(v.z >> 16); l.z = (u16)(v.z & 0xFFFF);
                h.w = (u16)(v.w >> 16); l.w = (u16)(v.w & 0xFFFF);
                *(ushort4*)(Qh + r * QROW + c) = h;
                *(ushort4*)(Ql + r * QROW + c) = l;
            }
        }
        // stage enc chunk 128x64 -> hi/lo
#pragma unroll
        for (int i = 0; i < 4; ++i) {
            int flat = (i * 512 + tid) * 4;
            int r = flat >> 6, c = flat & 63;
            float4 v = *(const float4*)(enc + (size_t)(b * 512 + ns * 128 + r) * 512 + dc * 64 + c);
            ushort4 h, l;
            h.x = bf16_rne(v.x); l.x = bf16_rne(v.x - bf2f(h.x));
            h.y = bf16_rne(v.y); l.y = bf16_rne(v.y - bf2f(h.y));
            h.z = bf16_rne(v.z); l.z = bf16_rne(v.z - bf2f(h.z));
            h.w = bf16_rne(v.w); l.w = bf16_rne(v.w - bf2f(h.w));
            *(ushort4*)(Eh + r * EROW + c) = h;
            *(ushort4*)(El + r * EROW + c) = l;
        }
        __syncthreads();
#pragma unroll
        for (int ks = 0; ks < 2; ++ks) {
            int ko = ks * 32 + lg * 8;
            bf16x8 ah = *(const bf16x8*)(Qh + (wm * 16 + ln) * QROW + ko);
            bf16x8 al = *(const bf16x8*)(Ql + (wm * 16 + ln) * QROW + ko);
#pragma unroll
            for (int nb = 0; nb < 4; ++nb) {
                int n = wn * 64 + nb * 16 + ln;
                bf16x8 bh = *(const bf16x8*)(Eh + n * EROW + ko);
                bf16x8 bl = *(const bf16x8*)(El + n * EROW + ko);
                int t = ns * 4 + nb;
                acc[t] = __builtin_amdgcn_mfma_f32_16x16x32_bf16(ah, bh, acc[t], 0, 0, 0);
                acc[t] = __builtin_amdgcn_mfma_f32_16x16x32_bf16(ah, bl, acc[t], 0, 0, 0);
                acc[t] = __builtin_amdgcn_mfma_f32_16x16x32_bf16(al, bh, acc[t], 0, 0, 0);
            }
        }
        __syncthreads();
    }

    // ---- Phase B: mask + two-pass softmax ----
#pragma unroll
    for (int t = 0; t < 16; ++t) {
        int s = (t >> 2) * 128 + wn * 64 + (t & 3) * 16 + ln;
        bool msk = mbyte ? (((const unsigned char*)maskraw)[b * 512 + s] != 0)
                         : (mi[b * 512 + s] != 0);
        if (msk) { acc[t][0] = -1e30f; acc[t][1] = -1e30f; acc[t][2] = -1e30f; acc[t][3] = -1e30f; }
    }
    int rbase = wm * 16 + lg * 4;
    float mx[4] = { -1e30f, -1e30f, -1e30f, -1e30f };
#pragma unroll
    for (int t = 0; t < 16; ++t)
#pragma unroll
        for (int j = 0; j < 4; ++j) mx[j] = fmaxf(mx[j], acc[t][j]);
#pragma unroll
    for (int d = 1; d < 16; d <<= 1)
#pragma unroll
        for (int j = 0; j < 4; ++j) mx[j] = fmaxf(mx[j], __shfl_xor(mx[j], d, 64));
    if (ln == 0)
#pragma unroll
        for (int j = 0; j < 4; ++j) scrM[wn * 64 + rbase + j] = mx[j];
    __syncthreads();
    float m4[4];
#pragma unroll
    for (int j = 0; j < 4; ++j) m4[j] = fmaxf(scrM[rbase + j], scrM[64 + rbase + j]);
    float sm[4] = { 0.f, 0.f, 0.f, 0.f };
#pragma unroll
    for (int t = 0; t < 16; ++t)
#pragma unroll
        for (int j = 0; j < 4; ++j) {
            float e = __expf(acc[t][j] - m4[j]);
            acc[t][j] = e;
            sm[j] += e;
        }
#pragma unroll
    for (int d = 1; d < 16; d <<= 1)
#pragma unroll
        for (int j = 0; j < 4; ++j) sm[j] += __shfl_xor(sm[j], d, 64);
    if (ln == 0)
#pragma unroll
        for (int j = 0; j < 4; ++j) scrS[wn * 64 + rbase + j] = sm[j];
    __syncthreads();
    float rinv[4];
#pragma unroll
    for (int j = 0; j < 4; ++j) rinv[j] = 1.0f / (scrS[rbase + j] + scrS[64 + rbase + j]);

    // weights (unnormalized exp, in (0,1]) -> LDS bf16
#pragma unroll
    for (int t = 0; t < 16; ++t) {
        int s = (t >> 2) * 128 + wn * 64 + (t & 3) * 16 + ln;
#pragma unroll
        for (int j = 0; j < 4; ++j)
            wlds[(rbase + j) * WROW + s] = bf16_rne(acc[t][j]);
    }
    __syncthreads();

    // ---- Phase C: ctx = weights @ enc ----
#pragma unroll
    for (int t = 0; t < 16; ++t) { acc[t][0]=0.f; acc[t][1]=0.f; acc[t][2]=0.f; acc[t][3]=0.f; }

    for (int sc = 0; sc < 16; ++sc) {
        if (sc) __syncthreads();
        // stage enc[sc*32 .. +32][:] transposed -> eldsT[d][s], coalesced lane-over-d loads
        {
            int d = tid;   // 512 threads == 512 d-columns
#pragma unroll
            for (int i = 0; i < 8; ++i) {
                size_t base = (size_t)(b * 512 + sc * 32 + i * 4) * 512 + d;
                float v0 = enc[base];
                float v1 = enc[base + 512];
                float v2 = enc[base + 1024];
                float v3 = enc[base + 1536];
                ushort4 h;
                h.x = bf16_rne(v0); h.y = bf16_rne(v1); h.z = bf16_rne(v2); h.w = bf16_rne(v3);
                *(ushort4*)(eldsT + d * TROW + i * 4) = h;
            }
        }
        __syncthreads();
        bf16x8 aw = *(const bf16x8*)(wlds + (wm * 16 + ln) * WROW + sc * 32 + lg * 8);
#pragma unroll
        for (int nb = 0; nb < 16; ++nb) {
            int d = wn * 256 + nb * 16 + ln;
            bf16x8 bv = *(const bf16x8*)(eldsT + d * TROW + lg * 8);
            acc[nb] = __builtin_amdgcn_mfma_f32_16x16x32_bf16(aw, bv, acc[nb], 0, 0, 0);
        }
    }

    // ---- epilogue: normalize and store ----
#pragma unroll
    for (int t = 0; t < 16; ++t) {
        int d = wn * 256 + t * 16 + ln;
#pragma unroll
        for (int j = 0; j < 4; ++j) {
            int p = rbase + j;
            out[(size_t)(brow0 + p) * 512 + d] = acc[t][j] * rinv[j];
        }
    }
}

extern "C" void kernel_launch(void* const* d_in, const int* in_sizes, int n_in,
                              void* d_out, int out_size, void* d_ws, size_t ws_size,
                              hipStream_t stream) {
    const float* enc  = (const float*)d_in[0];
    const float* dec  = (const float*)d_in[1];
    const void*  mask = d_in[2];
    const float* W    = (const float*)d_in[3];
    u32* qpk = (u32*)d_out;

    // K1: query GEMM (writes packed bf16 hi/lo query into d_out)
    k_query<<<dim3(1024), dim3(256), 4 * 128 * K1ROW * 2, stream>>>(dec, W, qpk);
    // K2: fused masked softmax attention (reads its own rows, then overwrites with context)
    size_t lds2 = (size_t)64 * WROW * 2 + (size_t)512 * TROW * 2 + 2 * 128 * 4 + 16;
    k_attn<<<dim3(512), dim3(512), lds2, stream>>>(enc, qpk, mask, (float*)d_out);
}

// Round 2
// 703.129 us; speedup vs baseline: 1.5184x; 1.5184x over previous
//
#include <hip/hip_runtime.h>
#include <hip/hip_bf16.h>
#include <stdint.h>

// Problem constants
#define NB    256   // batch
#define NSRC  512
#define NPRED 128
#define ND    512

typedef float  f32x4  __attribute__((ext_vector_type(4)));
typedef short  bf16x8 __attribute__((ext_vector_type(8)));
typedef unsigned short u16;
typedef unsigned int   u32;

__device__ __forceinline__ u16 bf16_rne(float x) {
    u32 u = __float_as_uint(x);
    u32 r = (u + 0x7FFFu + ((u >> 16) & 1u)) >> 16;
    return (u16)r;
}
__device__ __forceinline__ float bf2f(u16 h) {
    return __uint_as_float(((u32)h) << 16);
}

// ---------------------------------------------------------------------------
// K1: query = dec @ W^T  (M=32768, N=512, K=512), split-bf16 3-pass MFMA.
// Output: packed (hi<<16)|lo bf16 pair per element, written into d_out (u32).
// Tiles 128x128, BK=64, 256 threads (4 waves, 2x2).
// Register-prefetch pipeline: next K-tile's global loads issue before the
// MFMA block so HBM latency hides under MFMA + conversion VALU.
// ---------------------------------------------------------------------------
#define K1ROW 72   // LDS row pitch in shorts (64 data + 8 pad -> conflict-free b128)

__global__ __launch_bounds__(256, 2)
void k_query(const float* __restrict__ dec, const float* __restrict__ W,
             u32* __restrict__ qout)
{
    extern __shared__ u16 lds1[];
    u16* Ah = lds1;                  // [128][72]
    u16* Al = Ah + 128 * K1ROW;
    u16* Bh = Al + 128 * K1ROW;
    u16* Bl = Bh + 128 * K1ROW;

    int bid = blockIdx.x;                       // 1024 blocks
    int wg  = (bid & 7) * 128 + (bid >> 3);     // XCD swizzle (1024 = 8*128)
    int tm  = wg >> 2;                          // 0..255
    int tn  = wg & 3;                           // 0..3
    int tid  = threadIdx.x;
    int lane = tid & 63;
    int wid  = tid >> 6;
    int wr = wid >> 1, wc = wid & 1;
    int ln = lane & 15, lg = lane >> 4;

    f32x4 acc[4][4];
#pragma unroll
    for (int i = 0; i < 4; ++i)
#pragma unroll
        for (int j = 0; j < 4; ++j) { acc[i][j][0]=0.f; acc[i][j][1]=0.f; acc[i][j][2]=0.f; acc[i][j][3]=0.f; }

    // per-thread staging coords
    float4 pva[8], pvb[8];
#pragma unroll
    for (int i = 0; i < 8; ++i) {
        int flat = (i * 256 + tid) * 4;
        int r = flat >> 6, c = flat & 63;
        pva[i] = *(const float4*)(dec + (size_t)(tm * 128 + r) * 512 + 0 * 64 + c);
        pvb[i] = *(const float4*)(W   + (size_t)(tn * 128 + r) * 512 + 0 * 64 + c);
    }

    for (int kt = 0; kt < 8; ++kt) {
        if (kt) __syncthreads();   // protect LDS overwrite
        // convert current regs -> LDS hi/lo
#pragma unroll
        for (int i = 0; i < 8; ++i) {
            int flat = (i * 256 + tid) * 4;
            int r = flat >> 6, c = flat & 63;
            float4 va = pva[i];
            ushort4 h, l;
            h.x = bf16_rne(va.x); l.x = bf16_rne(va.x - bf2f(h.x));
            h.y = bf16_rne(va.y); l.y = bf16_rne(va.y - bf2f(h.y));
            h.z = bf16_rne(va.z); l.z = bf16_rne(va.z - bf2f(h.z));
            h.w = bf16_rne(va.w); l.w = bf16_rne(va.w - bf2f(h.w));
            *(ushort4*)(Ah + r * K1ROW + c) = h;
            *(ushort4*)(Al + r * K1ROW + c) = l;
            float4 vb = pvb[i];
            ushort4 hb, lb;
            hb.x = bf16_rne(vb.x); lb.x = bf16_rne(vb.x - bf2f(hb.x));
            hb.y = bf16_rne(vb.y); lb.y = bf16_rne(vb.y - bf2f(hb.y));
            hb.z = bf16_rne(vb.z); lb.z = bf16_rne(vb.z - bf2f(hb.z));
            hb.w = bf16_rne(vb.w); lb.w = bf16_rne(vb.w - bf2f(hb.w));
            *(ushort4*)(Bh + r * K1ROW + c) = hb;
            *(ushort4*)(Bl + r * K1ROW + c) = lb;
        }
        __syncthreads();
        // prefetch next K-tile while MFMA runs
        if (kt < 7) {
#pragma unroll
            for (int i = 0; i < 8; ++i) {
                int flat = (i * 256 + tid) * 4;
                int r = flat >> 6, c = flat & 63;
                pva[i] = *(const float4*)(dec + (size_t)(tm * 128 + r) * 512 + (kt + 1) * 64 + c);
                pvb[i] = *(const float4*)(W   + (size_t)(tn * 128 + r) * 512 + (kt + 1) * 64 + c);
            }
        }
#pragma unroll
        for (int ks = 0; ks < 2; ++ks) {
            int ko = ks * 32 + lg * 8;
            bf16x8 ah[4], al[4], bh[4], bl[4];
#pragma unroll
            for (int ms = 0; ms < 4; ++ms) {
                int m = wr * 64 + ms * 16 + ln;
                ah[ms] = *(const bf16x8*)(Ah + m * K1ROW + ko);
                al[ms] = *(const bf16x8*)(Al + m * K1ROW + ko);
            }
#pragma unroll
            for (int ns = 0; ns < 4; ++ns) {
                int n = wc * 64 + ns * 16 + ln;
                bh[ns] = *(const bf16x8*)(Bh + n * K1ROW + ko);
                bl[ns] = *(const bf16x8*)(Bl + n * K1ROW + ko);
            }
#pragma unroll
            for (int ms = 0; ms < 4; ++ms)
#pragma unroll
                for (int ns = 0; ns < 4; ++ns) {
                    acc[ms][ns] = __builtin_amdgcn_mfma_f32_16x16x32_bf16(ah[ms], bh[ns], acc[ms][ns], 0, 0, 0);
                    acc[ms][ns] = __builtin_amdgcn_mfma_f32_16x16x32_bf16(ah[ms], bl[ns], acc[ms][ns], 0, 0, 0);
                    acc[ms][ns] = __builtin_amdgcn_mfma_f32_16x16x32_bf16(al[ms], bh[ns], acc[ms][ns], 0, 0, 0);
                }
        }
    }
    // epilogue: pack query as bf16 hi/lo into u32
#pragma unroll
    for (int ms = 0; ms < 4; ++ms)
#pragma unroll
        for (int ns = 0; ns < 4; ++ns)
#pragma unroll
            for (int j = 0; j < 4; ++j) {
                int r = tm * 128 + wr * 64 + ms * 16 + lg * 4 + j;
                int c = tn * 128 + wc * 64 + ns * 16 + ln;
                float v = acc[ms][ns][j];
                u16 hi = bf16_rne(v);
                u16 lo = bf16_rne(v - bf2f(hi));
                qout[(size_t)r * 512 + c] = ((u32)hi << 16) | (u32)lo;
            }
}

// ---------------------------------------------------------------------------
// K2: fused scores + mask + softmax + PV.  One block = (b, 64 query rows).
// 512 threads = 8 waves (wm 0..3 over M, wn 0..1 over N).
// Phase A: S(64x512) in regs via split-bf16 3-pass -- ALL acc indices static
// (rule #20: runtime-indexed ext_vector arrays spill to scratch; that was the
// 1.9 GB WRITE_SIZE / VGPR=56 disaster in round 1).
// Phase B: two-pass softmax. Phase C: ctx = weights @ enc (transposed LDS).
// ---------------------------------------------------------------------------
#define QROW 72    // Qh/Ql row pitch (shorts)
#define EROW 72    // Eh/El row pitch (shorts)
#define WROW 528   // wlds row pitch (shorts): 512 + 16 pad
#define TROW 40    // eldsT row pitch (shorts): 32 + 8 pad

__global__ __launch_bounds__(512, 2)
void k_attn(const float* __restrict__ enc, const u32* qpk,
            const void* __restrict__ maskraw, float* out)
{
    extern __shared__ char smem[];
    u16* Qh = (u16*)smem;                         // [64][72]
    u16* Ql = Qh + 64 * QROW;
    u16* Eh = Ql + 64 * QROW;                     // [128][72]
    u16* El = Eh + 128 * EROW;
    u16* wlds  = (u16*)smem;                      // [64][528]  (phase C, overlaps phase A)
    u16* eldsT = (u16*)(smem + 64 * WROW * 2);    // [512][40]
    float* scrM = (float*)(smem + 64 * WROW * 2 + 512 * TROW * 2);  // [2][64]
    float* scrS = scrM + 128;                                        // [2][64]
    int* flagsh = (int*)(scrS + 128);

    int tid  = threadIdx.x;
    int lane = tid & 63, wid = tid >> 6;
    int wm = wid >> 1, wn = wid & 1;
    int ln = lane & 15, lg = lane >> 4;

    int bid = blockIdx.x;                    // 512 blocks
    int wg  = (bid & 7) * 64 + (bid >> 3);   // XCD swizzle: both halves of a b share an XCD
    int b   = wg >> 1;
    int ph  = wg & 1;
    int brow0 = b * 128 + ph * 64;

    // ---- mask element-size detection (1-byte vs 4-byte encodings) ----
    const int* mi = (const int*)maskraw;
    int bad = 0;
    for (int i = tid; i < 1024; i += 512) {
        int v = mi[i];
        if (!(v == 0 || v == 1 || v == 0x3F800000)) bad = 1;
    }
    if (tid == 0) *flagsh = 0;
    __syncthreads();
    if (bad) atomicOr(flagsh, 1);
    __syncthreads();
    const int mbyte = *flagsh;   // 1 -> byte layout, 0 -> 4-byte (int or f32; nonzero test works)

    // ---- Phase A: scores ----
    f32x4 acc[16];
#pragma unroll
    for (int t = 0; t < 16; ++t) { acc[t][0]=0.f; acc[t][1]=0.f; acc[t][2]=0.f; acc[t][3]=0.f; }

    for (int dc = 0; dc < 8; ++dc) {
        // stage Q chunk 64x64 (packed hi/lo)
#pragma unroll
        for (int i = 0; i < 2; ++i) {
            int flat = (i * 512 + tid) * 4;
            int r = flat >> 6, c = flat & 63;
            uint4 v = *(const uint4*)(qpk + (size_t)(brow0 + r) * 512 + dc * 64 + c);
            ushort4 h, l;
            h.x = (u16)(v.x >> 16); l.x = (u16)(v.x & 0xFFFF);
            h.y = (u16)(v.y >> 16); l.y = (u16)(v.y & 0xFFFF);
            h.z = (u16)(v.z >> 16); l.z = (u16)(v.z & 0xFFFF);
            h.w = (u16)(v.w >> 16); l.w = (u16)(v.w & 0xFFFF);
            *(ushort4*)(Qh + r * QROW + c) = h;
            *(ushort4*)(Ql + r * QROW + c) = l;
        }
#pragma unroll
        for (int ns = 0; ns < 4; ++ns) {        // COMPILE-TIME ns -> static acc idx
            // stage enc chunk 128x64 -> hi/lo
#pragma unroll
            for (int i = 0; i < 4; ++i) {
                int flat = (i * 512 + tid) * 4;
                int r = flat >> 6, c = flat & 63;
                float4 v = *(const float4*)(enc + (size_t)(b * 512 + ns * 128 + r) * 512 + dc * 64 + c);
                ushort4 h, l;
                h.x = bf16_rne(v.x); l.x = bf16_rne(v.x - bf2f(h.x));
                h.y = bf16_rne(v.y); l.y = bf16_rne(v.y - bf2f(h.y));
                h.z = bf16_rne(v.z); l.z = bf16_rne(v.z - bf2f(h.z));
                h.w = bf16_rne(v.w); l.w = bf16_rne(v.w - bf2f(h.w));
                *(ushort4*)(Eh + r * EROW + c) = h;
                *(ushort4*)(El + r * EROW + c) = l;
            }
            __syncthreads();
#pragma unroll
            for (int ks = 0; ks < 2; ++ks) {
                int ko = ks * 32 + lg * 8;
                bf16x8 ah = *(const bf16x8*)(Qh + (wm * 16 + ln) * QROW + ko);
                bf16x8 al = *(const bf16x8*)(Ql + (wm * 16 + ln) * QROW + ko);
#pragma unroll
                for (int nb = 0; nb < 4; ++nb) {
                    int n = wn * 64 + nb * 16 + ln;
                    bf16x8 bh = *(const bf16x8*)(Eh + n * EROW + ko);
                    bf16x8 bl = *(const bf16x8*)(El + n * EROW + ko);
                    acc[ns * 4 + nb] = __builtin_amdgcn_mfma_f32_16x16x32_bf16(ah, bh, acc[ns * 4 + nb], 0, 0, 0);
                    acc[ns * 4 + nb] = __builtin_amdgcn_mfma_f32_16x16x32_bf16(ah, bl, acc[ns * 4 + nb], 0, 0, 0);
                    acc[ns * 4 + nb] = __builtin_amdgcn_mfma_f32_16x16x32_bf16(al, bh, acc[ns * 4 + nb], 0, 0, 0);
                }
            }
            __syncthreads();
        }
    }

    // ---- Phase B: mask + two-pass softmax ----
#pragma unroll
    for (int t = 0; t < 16; ++t) {
        int s = (t >> 2) * 128 + wn * 64 + (t & 3) * 16 + ln;
        bool msk = mbyte ? (((const unsigned char*)maskraw)[b * 512 + s] != 0)
                         : (mi[b * 512 + s] != 0);
        if (msk) { acc[t][0] = -1e30f; acc[t][1] = -1e30f; acc[t][2] = -1e30f; acc[t][3] = -1e30f; }
    }
    int rbase = wm * 16 + lg * 4;
    float mx[4] = { -1e30f, -1e30f, -1e30f, -1e30f };
#pragma unroll
    for (int t = 0; t < 16; ++t)
#pragma unroll
        for (int j = 0; j < 4; ++j) mx[j] = fmaxf(mx[j], acc[t][j]);
#pragma unroll
    for (int d = 1; d < 16; d <<= 1)
#pragma unroll
        for (int j = 0; j < 4; ++j) mx[j] = fmaxf(mx[j], __shfl_xor(mx[j], d, 64));
    if (ln == 0)
#pragma unroll
        for (int j = 0; j < 4; ++j) scrM[wn * 64 + rbase + j] = mx[j];
    __syncthreads();
    float m4[4];
#pragma unroll
    for (int j = 0; j < 4; ++j) m4[j] = fmaxf(scrM[rbase + j], scrM[64 + rbase + j]);
    float sm[4] = { 0.f, 0.f, 0.f, 0.f };
#pragma unroll
    for (int t = 0; t < 16; ++t)
#pragma unroll
        for (int j = 0; j < 4; ++j) {
            float e = __expf(acc[t][j] - m4[j]);
            acc[t][j] = e;
            sm[j] += e;
        }
#pragma unroll
    for (int d = 1; d < 16; d <<= 1)
#pragma unroll
        for (int j = 0; j < 4; ++j) sm[j] += __shfl_xor(sm[j], d, 64);
    if (ln == 0)
#pragma unroll
        for (int j = 0; j < 4; ++j) scrS[wn * 64 + rbase + j] = sm[j];
    __syncthreads();
    float rinv[4];
#pragma unroll
    for (int j = 0; j < 4; ++j) rinv[j] = 1.0f / (scrS[rbase + j] + scrS[64 + rbase + j]);

    // weights (unnormalized exp, in (0,1]) -> LDS bf16
#pragma unroll
    for (int t = 0; t < 16; ++t) {
        int s = (t >> 2) * 128 + wn * 64 + (t & 3) * 16 + ln;
#pragma unroll
        for (int j = 0; j < 4; ++j)
            wlds[(rbase + j) * WROW + s] = bf16_rne(acc[t][j]);
    }
    __syncthreads();

    // ---- Phase C: ctx = weights @ enc ----
#pragma unroll
    for (int t = 0; t < 16; ++t) { acc[t][0]=0.f; acc[t][1]=0.f; acc[t][2]=0.f; acc[t][3]=0.f; }

    for (int sc = 0; sc < 16; ++sc) {
        if (sc) __syncthreads();
        // stage enc[sc*32 .. +32][:] transposed -> eldsT[d][s], coalesced lane-over-d loads
        {
            int d = tid;   // 512 threads == 512 d-columns
#pragma unroll
            for (int i = 0; i < 8; ++i) {
                size_t base = (size_t)(b * 512 + sc * 32 + i * 4) * 512 + d;
                float v0 = enc[base];
                float v1 = enc[base + 512];
                float v2 = enc[base + 1024];
                float v3 = enc[base + 1536];
                ushort4 h;
                h.x = bf16_rne(v0); h.y = bf16_rne(v1); h.z = bf16_rne(v2); h.w = bf16_rne(v3);
                *(ushort4*)(eldsT + d * TROW + i * 4) = h;
            }
        }
        __syncthreads();
        bf16x8 aw = *(const bf16x8*)(wlds + (wm * 16 + ln) * WROW + sc * 32 + lg * 8);
#pragma unroll
        for (int nb = 0; nb < 16; ++nb) {
            int d = wn * 256 + nb * 16 + ln;
            bf16x8 bv = *(const bf16x8*)(eldsT + d * TROW + lg * 8);
            acc[nb] = __builtin_amdgcn_mfma_f32_16x16x32_bf16(aw, bv, acc[nb], 0, 0, 0);
        }
    }

    // ---- epilogue: normalize and store ----
#pragma unroll
    for (int t = 0; t < 16; ++t) {
        int d = wn * 256 + t * 16 + ln;
#pragma unroll
        for (int j = 0; j < 4; ++j) {
            int p = rbase + j;
            out[(size_t)(brow0 + p) * 512 + d] = acc[t][j] * rinv[j];
        }
    }
}

extern "C" void kernel_launch(void* const* d_in, const int* in_sizes, int n_in,
                              void* d_out, int out_size, void* d_ws, size_t ws_size,
                              hipStream_t stream) {
    const float* enc  = (const float*)d_in[0];
    const float* dec  = (const float*)d_in[1];
    const void*  mask = d_in[2];
    const float* W    = (const float*)d_in[3];
    u32* qpk = (u32*)d_out;

    // K1: query GEMM (writes packed bf16 hi/lo query into d_out)
    k_query<<<dim3(1024), dim3(256), 4 * 128 * K1ROW * 2, stream>>>(dec, W, qpk);
    // K2: fused masked softmax attention (reads its own rows, then overwrites with context)
    size_t lds2 = (size_t)64 * WROW * 2 + (size_t)512 * TROW * 2 + 2 * 128 * 4 + 16;
    k_attn<<<dim3(512), dim3(512), lds2, stream>>>(enc, qpk, mask, (float*)d_out);
}

// Round 3
// 572.989 us; speedup vs baseline: 1.8633x; 1.2271x over previous
//
#include <hip/hip_runtime.h>
#include <hip/hip_bf16.h>
#include <stdint.h>

// Problem constants
#define NB    256   // batch
#define NSRC  512
#define NPRED 128
#define ND    512

typedef float  f32x4  __attribute__((ext_vector_type(4)));
typedef short  bf16x8 __attribute__((ext_vector_type(8)));
typedef unsigned short u16;
typedef unsigned int   u32;

__device__ __forceinline__ u16 bf16_rne(float x) {
    u32 u = __float_as_uint(x);
    u32 r = (u + 0x7FFFu + ((u >> 16) & 1u)) >> 16;
    return (u16)r;
}

// RTZ split: f = hi + lo + O(2^-16 |f|). hi = truncate-to-bf16, lo = truncate(f - hi).
// Safe for split-bf16 3-pass GEMM (residual f-hi is EXACT in f32; dropped al*bl <= 2^-16 rel).
__device__ __forceinline__ void split4(float4 v, uint2& hi, uint2& lo) {
    u32 u0 = __float_as_uint(v.x), u1 = __float_as_uint(v.y);
    u32 u2 = __float_as_uint(v.z), u3 = __float_as_uint(v.w);
    hi.x = (u0 >> 16) | (u1 & 0xFFFF0000u);
    hi.y = (u2 >> 16) | (u3 & 0xFFFF0000u);
    float r0 = v.x - __uint_as_float(u0 & 0xFFFF0000u);
    float r1 = v.y - __uint_as_float(u1 & 0xFFFF0000u);
    float r2 = v.z - __uint_as_float(u2 & 0xFFFF0000u);
    float r3 = v.w - __uint_as_float(u3 & 0xFFFF0000u);
    lo.x = (__float_as_uint(r0) >> 16) | (__float_as_uint(r1) & 0xFFFF0000u);
    lo.y = (__float_as_uint(r2) >> 16) | (__float_as_uint(r3) & 0xFFFF0000u);
}

// ---------------------------------------------------------------------------
// K1: query = dec @ W^T  (M=32768, N=512, K=512), split-bf16 3-pass MFMA.
// Tiles 128x128, BK=32, 256 threads (4 waves, 2x2). LDS 40KB -> 3 blocks/CU.
// Register prefetch (T14): next K-chunk's 8 float4 issue before the MFMA block.
// Output: packed (hi<<16)|lo bf16 pair per element (RTZ split), into d_out.
// ---------------------------------------------------------------------------
#define K1ROW 40   // LDS row pitch in shorts (32 data + 8 pad; 80B rows, 16B-aligned frags)

__global__ __launch_bounds__(256, 3)
void k_query(const float* __restrict__ dec, const float* __restrict__ W,
             u32* __restrict__ qout)
{
    extern __shared__ u16 lds1[];
    u16* Ah = lds1;                    // [128][40]
    u16* Al = Ah + 128 * K1ROW;
    u16* Bh = Al + 128 * K1ROW;
    u16* Bl = Bh + 128 * K1ROW;

    int bid = blockIdx.x;                       // 1024 blocks
    int wg  = (bid & 7) * 128 + (bid >> 3);     // XCD swizzle (1024 = 8*128)
    int tm  = wg >> 2;                          // 0..255
    int tn  = wg & 3;                           // 0..3
    int tid  = threadIdx.x;
    int lane = tid & 63;
    int wid  = tid >> 6;
    int wr = wid >> 1, wc = wid & 1;
    int ln = lane & 15, lg = lane >> 4;

    const float* decb = dec + (size_t)tm * 128 * 512;
    const float* Wb   = W   + (size_t)tn * 128 * 512;

    f32x4 acc[4][4];
#pragma unroll
    for (int i = 0; i < 4; ++i)
#pragma unroll
        for (int j = 0; j < 4; ++j) { acc[i][j][0]=0.f; acc[i][j][1]=0.f; acc[i][j][2]=0.f; acc[i][j][3]=0.f; }

    float4 pa[4], pb[4];
#pragma unroll
    for (int i = 0; i < 4; ++i) {
        int flat = (i * 256 + tid) * 4;
        int r = flat >> 5, c = flat & 31;
        pa[i] = *(const float4*)(decb + (size_t)r * 512 + c);
        pb[i] = *(const float4*)(Wb   + (size_t)r * 512 + c);
    }

    for (int kt = 0; kt < 16; ++kt) {
        if (kt) __syncthreads();       // prev MFMA readers done
#pragma unroll
        for (int i = 0; i < 4; ++i) {
            int flat = (i * 256 + tid) * 4;
            int r = flat >> 5, c = flat & 31;
            uint2 h, l;
            split4(pa[i], h, l);
            *(uint2*)(Ah + r * K1ROW + c) = h;
            *(uint2*)(Al + r * K1ROW + c) = l;
            split4(pb[i], h, l);
            *(uint2*)(Bh + r * K1ROW + c) = h;
            *(uint2*)(Bl + r * K1ROW + c) = l;
        }
        __syncthreads();               // LDS ready
        if (kt < 15) {                 // prefetch next chunk; flies during MFMA
#pragma unroll
            for (int i = 0; i < 4; ++i) {
                int flat = (i * 256 + tid) * 4;
                int r = flat >> 5, c = flat & 31;
                pa[i] = *(const float4*)(decb + (size_t)r * 512 + (kt + 1) * 32 + c);
                pb[i] = *(const float4*)(Wb   + (size_t)r * 512 + (kt + 1) * 32 + c);
            }
        }
        int ko = lg * 8;
        bf16x8 ah[4], al[4];
#pragma unroll
        for (int ms = 0; ms < 4; ++ms) {
            int m = wr * 64 + ms * 16 + ln;
            ah[ms] = *(const bf16x8*)(Ah + m * K1ROW + ko);
            al[ms] = *(const bf16x8*)(Al + m * K1ROW + ko);
        }
#pragma unroll
        for (int ns = 0; ns < 4; ++ns) {
            int n = wc * 64 + ns * 16 + ln;
            bf16x8 bh = *(const bf16x8*)(Bh + n * K1ROW + ko);
            bf16x8 bl = *(const bf16x8*)(Bl + n * K1ROW + ko);
#pragma unroll
            for (int ms = 0; ms < 4; ++ms) {
                acc[ms][ns] = __builtin_amdgcn_mfma_f32_16x16x32_bf16(ah[ms], bh, acc[ms][ns], 0, 0, 0);
                acc[ms][ns] = __builtin_amdgcn_mfma_f32_16x16x32_bf16(ah[ms], bl, acc[ms][ns], 0, 0, 0);
                acc[ms][ns] = __builtin_amdgcn_mfma_f32_16x16x32_bf16(al[ms], bh, acc[ms][ns], 0, 0, 0);
            }
        }
    }
    // epilogue: pack query as RTZ hi/lo into u32
#pragma unroll
    for (int ms = 0; ms < 4; ++ms)
#pragma unroll
        for (int ns = 0; ns < 4; ++ns)
#pragma unroll
            for (int j = 0; j < 4; ++j) {
                int r = tm * 128 + wr * 64 + ms * 16 + lg * 4 + j;
                int c = tn * 128 + wc * 64 + ns * 16 + ln;
                float v = acc[ms][ns][j];
                u32 u  = __float_as_uint(v);
                u32 hi = u >> 16;
                float rres = v - __uint_as_float(u & 0xFFFF0000u);
                u32 lo = __float_as_uint(rres) >> 16;
                qout[(size_t)r * 512 + c] = (hi << 16) | lo;
            }
}

// ---------------------------------------------------------------------------
// K2: fused scores + mask + softmax + PV.  One block = (b, 64 query rows).
// 512 threads = 8 waves (wm 0..3 over M, wn 0..1 over N).
// Phase A: S(64x512) in regs, split-bf16 3-pass, static acc indices,
//          register-prefetched staging (enc + Q chunks fly during MFMA).
// Phase B: two-pass softmax. Phase C: ctx = weights @ enc (transposed LDS).
// ---------------------------------------------------------------------------
#define QROW 72    // Qh/Ql row pitch (shorts)
#define EROW 72    // Eh/El row pitch (shorts)
#define WROW 520   // wlds row pitch (shorts): 512 + 8 pad (1040B rows -> 2-way free reads)
#define TROW 36    // eldsT row pitch (shorts): 32 + 4 pad (72B rows; write conflicts 8->4-way)

__global__ __launch_bounds__(512, 2)
void k_attn(const float* __restrict__ enc, const u32* qpk,
            const void* __restrict__ maskraw, float* out)
{
    extern __shared__ char smem[];
    u16* Qh = (u16*)smem;                         // [64][72]
    u16* Ql = Qh + 64 * QROW;
    u16* Eh = Ql + 64 * QROW;                     // [128][72]
    u16* El = Eh + 128 * EROW;
    u16* wlds  = (u16*)smem;                      // [64][520]  (phase C, overlaps phase A)
    u16* eldsT = (u16*)(smem + 64 * WROW * 2);    // [512][36]
    float* scrM = (float*)(smem + 64 * WROW * 2 + 512 * TROW * 2);  // [2][64]
    float* scrS = scrM + 128;                                        // [2][64]
    int* flagsh = (int*)(scrS + 128);

    int tid  = threadIdx.x;
    int lane = tid & 63, wid = tid >> 6;
    int wm = wid >> 1, wn = wid & 1;
    int ln = lane & 15, lg = lane >> 4;

    int bid = blockIdx.x;                    // 512 blocks
    int wg  = (bid & 7) * 64 + (bid >> 3);   // XCD swizzle: both halves of a b share an XCD
    int b   = wg >> 1;
    int ph  = wg & 1;
    int brow0 = b * 128 + ph * 64;

    // ---- mask element-size detection (1-byte vs 4-byte encodings) ----
    const int* mi = (const int*)maskraw;
    int bad = 0;
    for (int i = tid; i < 1024; i += 512) {
        int v = mi[i];
        if (!(v == 0 || v == 1 || v == 0x3F800000)) bad = 1;
    }
    if (tid == 0) *flagsh = 0;
    __syncthreads();
    if (bad) atomicOr(flagsh, 1);
    __syncthreads();
    const int mbyte = *flagsh;   // 1 -> byte layout, 0 -> 4-byte (int or f32; nonzero test works)

    // ---- Phase A: scores (prefetched staging) ----
    f32x4 acc[16];
#pragma unroll
    for (int t = 0; t < 16; ++t) { acc[t][0]=0.f; acc[t][1]=0.f; acc[t][2]=0.f; acc[t][3]=0.f; }

    // per-thread staging coords
    int eflat = tid * 4;
    int qr0 = (0 * 512 + tid) * 4 >> 6;   // q: i in 0..2
    // preload step (dc=0, ns=0) + Q chunk dc=0
    float4 pe[4];
    uint4  pq[2];
#pragma unroll
    for (int i = 0; i < 4; ++i) {
        int flat = (i * 512 + tid) * 4;
        int r = flat >> 6, c = flat & 63;
        pe[i] = *(const float4*)(enc + (size_t)(b * 512 + 0 * 128 + r) * 512 + 0 * 64 + c);
    }
#pragma unroll
    for (int i = 0; i < 2; ++i) {
        int flat = (i * 512 + tid) * 4;
        int r = flat >> 6, c = flat & 63;
        pq[i] = *(const uint4*)(qpk + (size_t)(brow0 + r) * 512 + 0 * 64 + c);
    }
    (void)eflat; (void)qr0;

    for (int dc = 0; dc < 8; ++dc) {
#pragma unroll
        for (int ns = 0; ns < 4; ++ns) {
            if (dc || ns) __syncthreads();     // prev MFMA readers done; LDS writable
            if (ns == 0) {
                // unpack Q chunk 64x64 (packed hi/lo) from pq
#pragma unroll
                for (int i = 0; i < 2; ++i) {
                    int flat = (i * 512 + tid) * 4;
                    int r = flat >> 6, c = flat & 63;
                    uint4 v = pq[i];
                    uint2 h, l;
                    h.x = (v.x >> 16) | (v.y & 0xFFFF0000u);
                    h.y = (v.z >> 16) | (v.w & 0xFFFF0000u);
                    l.x = (v.x & 0xFFFFu) | (v.y << 16);
                    l.y = (v.z & 0xFFFFu) | (v.w << 16);
                    *(uint2*)(Qh + r * QROW + c) = h;
                    *(uint2*)(Ql + r * QROW + c) = l;
                }
            }
            // convert enc chunk 128x64 (from pe) -> hi/lo planes
#pragma unroll
            for (int i = 0; i < 4; ++i) {
                int flat = (i * 512 + tid) * 4;
                int r = flat >> 6, c = flat & 63;
                uint2 h, l;
                split4(pe[i], h, l);
                *(uint2*)(Eh + r * EROW + c) = h;
                *(uint2*)(El + r * EROW + c) = l;
            }
            __syncthreads();                   // LDS ready
            // prefetch next step's enc (and Q at dc boundary); flies during MFMA
            if (!(dc == 7 && ns == 3)) {
                int ndc = (ns == 3) ? dc + 1 : dc;
                int nns = (ns == 3) ? 0 : ns + 1;
#pragma unroll
                for (int i = 0; i < 4; ++i) {
                    int flat = (i * 512 + tid) * 4;
                    int r = flat >> 6, c = flat & 63;
                    pe[i] = *(const float4*)(enc + (size_t)(b * 512 + nns * 128 + r) * 512 + ndc * 64 + c);
                }
                if (ns == 3) {
#pragma unroll
                    for (int i = 0; i < 2; ++i) {
                        int flat = (i * 512 + tid) * 4;
                        int r = flat >> 6, c = flat & 63;
                        pq[i] = *(const uint4*)(qpk + (size_t)(brow0 + r) * 512 + (dc + 1) * 64 + c);
                    }
                }
            }
#pragma unroll
            for (int ks = 0; ks < 2; ++ks) {
                int ko = ks * 32 + lg * 8;
                bf16x8 ah = *(const bf16x8*)(Qh + (wm * 16 + ln) * QROW + ko);
                bf16x8 al = *(const bf16x8*)(Ql + (wm * 16 + ln) * QROW + ko);
#pragma unroll
                for (int nb = 0; nb < 4; ++nb) {
                    int n = wn * 64 + nb * 16 + ln;
                    bf16x8 bh = *(const bf16x8*)(Eh + n * EROW + ko);
                    bf16x8 bl = *(const bf16x8*)(El + n * EROW + ko);
                    acc[ns * 4 + nb] = __builtin_amdgcn_mfma_f32_16x16x32_bf16(ah, bh, acc[ns * 4 + nb], 0, 0, 0);
                    acc[ns * 4 + nb] = __builtin_amdgcn_mfma_f32_16x16x32_bf16(ah, bl, acc[ns * 4 + nb], 0, 0, 0);
                    acc[ns * 4 + nb] = __builtin_amdgcn_mfma_f32_16x16x32_bf16(al, bh, acc[ns * 4 + nb], 0, 0, 0);
                }
            }
        }
    }

    // ---- Phase B: mask + two-pass softmax ----
#pragma unroll
    for (int t = 0; t < 16; ++t) {
        int s = (t >> 2) * 128 + wn * 64 + (t & 3) * 16 + ln;
        bool msk = mbyte ? (((const unsigned char*)maskraw)[b * 512 + s] != 0)
                         : (mi[b * 512 + s] != 0);
        if (msk) { acc[t][0] = -1e30f; acc[t][1] = -1e30f; acc[t][2] = -1e30f; acc[t][3] = -1e30f; }
    }
    int rbase = wm * 16 + lg * 4;
    float mx[4] = { -1e30f, -1e30f, -1e30f, -1e30f };
#pragma unroll
    for (int t = 0; t < 16; ++t)
#pragma unroll
        for (int j = 0; j < 4; ++j) mx[j] = fmaxf(mx[j], acc[t][j]);
#pragma unroll
    for (int d = 1; d < 16; d <<= 1)
#pragma unroll
        for (int j = 0; j < 4; ++j) mx[j] = fmaxf(mx[j], __shfl_xor(mx[j], d, 64));
    if (ln == 0)
#pragma unroll
        for (int j = 0; j < 4; ++j) scrM[wn * 64 + rbase + j] = mx[j];
    __syncthreads();
    float m4[4];
#pragma unroll
    for (int j = 0; j < 4; ++j) m4[j] = fmaxf(scrM[rbase + j], scrM[64 + rbase + j]);
    float sm[4] = { 0.f, 0.f, 0.f, 0.f };
#pragma unroll
    for (int t = 0; t < 16; ++t)
#pragma unroll
        for (int j = 0; j < 4; ++j) {
            float e = __expf(acc[t][j] - m4[j]);
            acc[t][j] = e;
            sm[j] += e;
        }
#pragma unroll
    for (int d = 1; d < 16; d <<= 1)
#pragma unroll
        for (int j = 0; j < 4; ++j) sm[j] += __shfl_xor(sm[j], d, 64);
    if (ln == 0)
#pragma unroll
        for (int j = 0; j < 4; ++j) scrS[wn * 64 + rbase + j] = sm[j];
    __syncthreads();
    float rinv[4];
#pragma unroll
    for (int j = 0; j < 4; ++j) rinv[j] = 1.0f / (scrS[rbase + j] + scrS[64 + rbase + j]);

    // weights (unnormalized exp, in (0,1]) -> LDS bf16 (RNE: accuracy-critical)
#pragma unroll
    for (int t = 0; t < 16; ++t) {
        int s = (t >> 2) * 128 + wn * 64 + (t & 3) * 16 + ln;
#pragma unroll
        for (int j = 0; j < 4; ++j)
            wlds[(rbase + j) * WROW + s] = bf16_rne(acc[t][j]);
    }
    __syncthreads();

    // ---- Phase C: ctx = weights @ enc ----
#pragma unroll
    for (int t = 0; t < 16; ++t) { acc[t][0]=0.f; acc[t][1]=0.f; acc[t][2]=0.f; acc[t][3]=0.f; }

    for (int sc = 0; sc < 16; ++sc) {
        if (sc) __syncthreads();
        // stage enc[sc*32 .. +32][:] transposed -> eldsT[d][s], coalesced lane-over-d loads
        {
            int d = tid;   // 512 threads == 512 d-columns
#pragma unroll
            for (int i = 0; i < 8; ++i) {
                size_t base = (size_t)(b * 512 + sc * 32 + i * 4) * 512 + d;
                float v0 = enc[base];
                float v1 = enc[base + 512];
                float v2 = enc[base + 1024];
                float v3 = enc[base + 1536];
                ushort4 h;
                h.x = bf16_rne(v0); h.y = bf16_rne(v1); h.z = bf16_rne(v2); h.w = bf16_rne(v3);
                *(ushort4*)(eldsT + d * TROW + i * 4) = h;   // 72B rows: 8B-aligned
            }
        }
        __syncthreads();
        bf16x8 aw = *(const bf16x8*)(wlds + (wm * 16 + ln) * WROW + sc * 32 + lg * 8);
#pragma unroll
        for (int nb = 0; nb < 16; ++nb) {
            int d = wn * 256 + nb * 16 + ln;
            const u16* bp = eldsT + d * TROW + lg * 8;
            uint2 b0 = *(const uint2*)(bp);       // rows are 8B-aligned, not 16B
            uint2 b1 = *(const uint2*)(bp + 4);
            union { uint4 u; bf16x8 v; } cv;
            cv.u.x = b0.x; cv.u.y = b0.y; cv.u.z = b1.x; cv.u.w = b1.y;
            acc[nb] = __builtin_amdgcn_mfma_f32_16x16x32_bf16(aw, cv.v, acc[nb], 0, 0, 0);
        }
    }

    // ---- epilogue: normalize and store ----
#pragma unroll
    for (int t = 0; t < 16; ++t) {
        int d = wn * 256 + t * 16 + ln;
#pragma unroll
        for (int j = 0; j < 4; ++j) {
            int p = rbase + j;
            out[(size_t)(brow0 + p) * 512 + d] = acc[t][j] * rinv[j];
        }
    }
}

extern "C" void kernel_launch(void* const* d_in, const int* in_sizes, int n_in,
                              void* d_out, int out_size, void* d_ws, size_t ws_size,
                              hipStream_t stream) {
    const float* enc  = (const float*)d_in[0];
    const float* dec  = (const float*)d_in[1];
    const void*  mask = d_in[2];
    const float* W    = (const float*)d_in[3];
    u32* qpk = (u32*)d_out;

    // K1: query GEMM (writes packed bf16 hi/lo query into d_out)
    k_query<<<dim3(1024), dim3(256), 4 * 128 * K1ROW * 2, stream>>>(dec, W, qpk);
    // K2: fused masked softmax attention (reads its own rows, then overwrites with context)
    size_t lds2 = (size_t)64 * WROW * 2 + (size_t)512 * TROW * 2 + 2 * 128 * 4 + 16;
    k_attn<<<dim3(512), dim3(512), lds2, stream>>>(enc, qpk, mask, (float*)d_out);
}